// Round 22
// baseline (222.235 us; speedup 1.0000x reference)
//
#include <hip/hip_runtime.h>

#define NN 50000
#define NPAD 50064             // padded rows (>= NN+64) for MFMA tail + zero pad row
#define EE 800000
#define DD 64
#define BN_EPS 1e-5f

#define NPART 8
#define PART_NODES 6250        // 50000/8
#define CAP 64                 // padded CSR slots per node (u16)
#define SENT2 0xC350C350u      // two u16 sentinels (50000,50000)
#define BCAP 131072            // bucket capacity per partition (u32 entries)
#define NSCAT 32               // scatter blocks per partition
#define NB_BUILD 782           // ceil(800000/1024)
#define NBT 800768             // NB_BUILD*1024 build threads
#define NB_AGG  12500          // 4 nodes (waves) per 256-thr block, grid exact
#define NB_MLP  782            // 64 rows per block (4 waves x 16)
#define NB_APPLY 3125

typedef __attribute__((ext_vector_type(8))) short short8v;   // 8 bf16 = 4 VGPR
typedef __attribute__((ext_vector_type(4))) float float4v;   // MFMA acc

__device__ __forceinline__ unsigned bfpack2(float a, float b) {
    union { float f; unsigned u; } ua, ub;
    ua.f = a; ub.f = b;
    unsigned ra = ua.u + 0x7fffu + ((ua.u >> 16) & 1u);
    unsigned rb = ub.u + 0x7fffu + ((ub.u >> 16) & 1u);
    return (ra >> 16) | (rb & 0xffff0000u);
}

__device__ __forceinline__ unsigned short bf16of(float v) {
    union { float f; unsigned u; } x; x.f = v;
    unsigned r = x.u + 0x7fffu + ((x.u >> 16) & 1u);
    return (unsigned short)(r >> 16);
}

// zero small control state (bucketCnt + 3x128 stats)
__global__ void k_zero(int* __restrict__ bucketCnt, float* __restrict__ stats) {
    int t = threadIdx.x;
    if (t < 128) bucketCnt[t] = 0;
    if (t < 384) stats[t] = 0.f;
}

// build: bucket edges by dst partition (u32-packed s<<13|dlocal), zero cursor,
// cvt x -> bf16, prep W -> bf16, sentinel-fill col (u16) + zero pad rows.
__global__ __launch_bounds__(1024) void k_build(const int* __restrict__ src,
                                                const int* __restrict__ dst,
                                                unsigned* __restrict__ bucket,
                                                int* __restrict__ bucketCnt,
                                                int* __restrict__ cursor,
                                                const float* __restrict__ x,
                                                unsigned* __restrict__ xb,
                                                unsigned* __restrict__ mb,
                                                unsigned short* __restrict__ col,
                                                const float* __restrict__ W1,
                                                const float* __restrict__ W2,
                                                unsigned short* __restrict__ Wb) {
    __shared__ int lcnt[8];
    __shared__ int lbase[8];
    int t = threadIdx.x;
    int g = blockIdx.x * 1024 + t;
    if (g < NN) cursor[g] = 0;
    if (g < NN * 8) {
        const float4* p = (const float4*)(x + (size_t)g * 8);
        float4 a = p[0], b = p[1];
        uint4 o;
        o.x = bfpack2(a.x, a.y); o.y = bfpack2(a.z, a.w);
        o.z = bfpack2(b.x, b.y); o.w = bfpack2(b.z, b.w);
        ((uint4*)xb)[g] = o;
    }
    if (g < 3 * 2 * 4096) {
        int l = g / 8192;
        int rem = g - l * 8192;
        int m = rem / 4096;
        int e = rem - m * 4096;
        int c = e >> 6, k = e & 63;
        const float* W = (m == 0 ? W1 : W2) + l * 4096;
        Wb[g] = bf16of(W[k * 64 + c]);
    }
    // sentinel-fill first 32 u16 slots of every node (16 u32 writes per node)
    {
        unsigned* col32 = (unsigned*)col;
        if (g < NN * 16)
            col32[(g >> 4) * 32 + (g & 15)] = SENT2;
    }
    // zero the pad rows (row NN..) so sentinel gathers read 0
    if (g < 64 * 32) { xb[NN * 32 + g] = 0; mb[NN * 32 + g] = 0; }
    if (t < 8) lcnt[t] = 0;
    __syncthreads();
    int p = 0, loc = 0;
    unsigned pk = 0;
    bool ok = (g < EE);
    if (ok) {
        int d = __builtin_nontemporal_load(dst + g);
        int s = __builtin_nontemporal_load(src + g);
        p = (unsigned)d / PART_NODES;
        pk = ((unsigned)s << 13) | (unsigned)(d - p * PART_NODES);
        loc = atomicAdd(&lcnt[p], 1);
    }
    __syncthreads();
    if (t < 8) lbase[t] = atomicAdd(&bucketCnt[t * 16], lcnt[t]);
    __syncthreads();
    if (ok) bucket[(size_t)p * BCAP + lbase[p] + loc] = pk;
}

// scatter bucket p into col slice p (u16 stores; dirty lines stay on one XCD)
__global__ __launch_bounds__(256) void k_scatter(const unsigned* __restrict__ bucket,
                                                 const int* __restrict__ bucketCnt,
                                                 int* __restrict__ cursor,
                                                 unsigned short* __restrict__ col) {
    int p = blockIdx.x & 7;
    int cnt = bucketCnt[p * 16];
    int dbase = p * PART_NODES;
    const unsigned* b = bucket + (size_t)p * BCAP;
    for (int i = (blockIdx.x >> 3) * 256 + threadIdx.x; i < cnt; i += NSCAT * 256) {
        unsigned v = __builtin_nontemporal_load(b + i);
        int d = dbase + (int)(v & 8191u);
        int s = (int)(v >> 13);
        int pos = atomicAdd(&cursor[d], 1);
        col[d * CAP + pos] = (unsigned short)s;
    }
}

// z[i,:] = self + sum_j val(h[j,:]); val = relu(a*x+c) when FUSE.
// Branchless first 32 slots: u16 col pad holds sentinel NN -> zeroed pad row,
// contribution cancelled via fmaf(mask,...). 4 col loads + 4 gathers issue
// with NO deg dependency — deg only gates the rare >32 tail.
template<int FUSE>
__global__ __launch_bounds__(256) void k_agg4(const unsigned* __restrict__ hb,
                                              const int* __restrict__ deg,
                                              const unsigned short* __restrict__ col,
                                              const float* __restrict__ statsL,
                                              const float* __restrict__ gammaL,
                                              const float* __restrict__ betaL,
                                              unsigned* __restrict__ outZb) {
    __shared__ float sa[64];
    __shared__ float sc[64];
    if (FUSE) {
        int tt = threadIdx.x;
        if (tt < 64) {
            float mean = statsL[tt] * (1.f / NN);
            float var = statsL[64 + tt] * (1.f / NN) - mean * mean;
            float a = gammaL[tt] * rsqrtf(var + BN_EPS);
            sa[tt] = a;
            sc[tt] = fmaf(-mean, a, betaL[tt]);
        }
        __syncthreads();
    }
    int node = blockIdx.x * 4 + (threadIdx.x >> 6);   // grid exact: 12500*4
    int lane = threadIdx.x & 63;
    int li = lane & 7;
    int slot = lane >> 3;
    int base = node * CAP;
    // 4 independent u16 col loads, issued before anything depends on deg
    int s0 = col[base + slot];
    int s1 = col[base + slot + 8];
    int s2 = col[base + slot + 16];
    int s3 = col[base + slot + 24];
    int dn = deg[node];            // only gates the rare >32 tail
    const uint4* hb4 = (const uint4*)hb;
    uint4 u0 = hb4[(size_t)s0 * 8 + li];
    uint4 u1 = hb4[(size_t)s1 * 8 + li];
    uint4 u2 = hb4[(size_t)s2 * 8 + li];
    uint4 u3 = hb4[(size_t)s3 * 8 + li];
    float m0 = (s0 < NN) ? 1.f : 0.f;
    float m1 = (s1 < NN) ? 1.f : 0.f;
    float m2 = (s2 < NN) ? 1.f : 0.f;
    float m3 = (s3 < NN) ? 1.f : 0.f;

    float a8[8], c8[8];
    if (FUSE) {
#pragma unroll
        for (int j = 0; j < 8; ++j) { a8[j] = sa[li * 8 + j]; c8[j] = sc[li * 8 + j]; }
    }
    float acc[8];
#pragma unroll
    for (int i = 0; i < 8; ++i) acc[i] = 0.f;

#define UNPK_ADD_M(U, M)                                                 \
    {                                                                    \
        uint4 _u = (U);                                                  \
        union { unsigned u; float f; } l0, h0, l1, h1, l2, h2, l3, h3;   \
        l0.u = _u.x << 16; h0.u = _u.x & 0xffff0000u;                    \
        l1.u = _u.y << 16; h1.u = _u.y & 0xffff0000u;                    \
        l2.u = _u.z << 16; h2.u = _u.z & 0xffff0000u;                    \
        l3.u = _u.w << 16; h3.u = _u.w & 0xffff0000u;                    \
        float v[8] = {l0.f, h0.f, l1.f, h1.f, l2.f, h2.f, l3.f, h3.f};   \
        _Pragma("unroll")                                                \
        for (int j = 0; j < 8; ++j) {                                    \
            float y = FUSE ? fmaxf(fmaf(v[j], a8[j], c8[j]), 0.f) : v[j];\
            acc[j] = fmaf((M), y, acc[j]);                               \
        }                                                                \
    }

    if (slot == 0)
        UNPK_ADD_M(hb4[(size_t)node * 8 + li], 1.f);   // self row

    UNPK_ADD_M(u0, m0);
    UNPK_ADD_M(u1, m1);
    UNPK_ADD_M(u2, m2);
    UNPK_ADD_M(u3, m3);

    if (dn > 32) {                 // rare tail
        for (int k = 32 + slot; k < dn; k += 8) {
            int s = col[base + k];
            UNPK_ADD_M(hb4[(size_t)s * 8 + li], 1.f);
        }
    }
#undef UNPK_ADD_M

#pragma unroll
    for (int i = 0; i < 8; ++i) acc[i] += __shfl_xor(acc[i], 8);
#pragma unroll
    for (int i = 0; i < 8; ++i) acc[i] += __shfl_xor(acc[i], 16);
#pragma unroll
    for (int i = 0; i < 8; ++i) acc[i] += __shfl_xor(acc[i], 32);

    if (slot == 0) {
        uint4 o;
        o.x = bfpack2(acc[0], acc[1]);
        o.y = bfpack2(acc[2], acc[3]);
        o.z = bfpack2(acc[4], acc[5]);
        o.w = bfpack2(acc[6], acc[7]);
        ((uint4*)outZb)[(size_t)node * 8 + li] = o;
    }
}

// MFMA MLP + fused BN stats; always writes bf16 Mb (LDS repack, 16B stores).
// Stats from f32 acc2 (exact).
__global__ __launch_bounds__(256) void k_mlp_mfma(const unsigned short* __restrict__ Zb,
                                                  const unsigned short* __restrict__ WbL,
                                                  const float* __restrict__ b1,
                                                  const float* __restrict__ b2,
                                                  unsigned short* __restrict__ Mb,
                                                  float* __restrict__ statsL) {
    __shared__ unsigned short sm[4][16 * 72];   // padded stride 72 u16
    __shared__ float sred[2][4][64];
    int w = threadIdx.x >> 6;
    int lane = threadIdx.x & 63;
    int q = lane >> 4;
    int cl = lane & 15;
    int r0 = blockIdx.x * 64 + w * 16;

    short8v B1[4][2], B2[4][2];
#pragma unroll
    for (int t = 0; t < 4; ++t) {
#pragma unroll
        for (int h = 0; h < 2; ++h) {
            B1[t][h] = *(const short8v*)(WbL + ((t * 16 + cl) * 64 + h * 32 + q * 8));
            B2[t][h] = *(const short8v*)(WbL + 4096 + ((t * 16 + cl) * 64 + h * 32 + q * 8));
        }
    }

    const unsigned short* zr = Zb + (size_t)(r0 + cl) * 64;
    short8v a0 = *(const short8v*)(zr + q * 8);
    short8v a1 = *(const short8v*)(zr + 32 + q * 8);

    float4v acc1[4];
#pragma unroll
    for (int t = 0; t < 4; ++t) {
        float b = b1[t * 16 + cl];
        acc1[t] = (float4v){b, b, b, b};
        acc1[t] = __builtin_amdgcn_mfma_f32_16x16x32_bf16(a0, B1[t][0], acc1[t], 0, 0, 0);
        acc1[t] = __builtin_amdgcn_mfma_f32_16x16x32_bf16(a1, B1[t][1], acc1[t], 0, 0, 0);
    }

    unsigned short* s = sm[w];
#pragma unroll
    for (int t = 0; t < 4; ++t) {
#pragma unroll
        for (int r = 0; r < 4; ++r) {
            float v = fmaxf(acc1[t][r], 0.f);
            s[(q * 4 + r) * 72 + t * 16 + cl] = bf16of(v);
        }
    }

    short8v a2_0 = *(const short8v*)(s + cl * 72 + q * 8);
    short8v a2_1 = *(const short8v*)(s + cl * 72 + 32 + q * 8);

    float4v acc2[4];
#pragma unroll
    for (int t = 0; t < 4; ++t) {
        float b = b2[t * 16 + cl];
        acc2[t] = (float4v){b, b, b, b};
        acc2[t] = __builtin_amdgcn_mfma_f32_16x16x32_bf16(a2_0, B2[t][0], acc2[t], 0, 0, 0);
        acc2[t] = __builtin_amdgcn_mfma_f32_16x16x32_bf16(a2_1, B2[t][1], acc2[t], 0, 0, 0);
    }

    // bf16 repack through LDS tile -> 16B coalesced stores
#pragma unroll
    for (int t = 0; t < 4; ++t) {
#pragma unroll
        for (int r = 0; r < 4; ++r) {
            s[(q * 4 + r) * 72 + t * 16 + cl] = bf16of(acc2[t][r]);
        }
    }
    short8v m0 = *(const short8v*)(s + cl * 72 + q * 8);
    short8v m1 = *(const short8v*)(s + cl * 72 + 32 + q * 8);
    int orow = r0 + cl;
    if (orow < NN) {
        *(short8v*)(Mb + (size_t)orow * 64 + q * 8) = m0;
        *(short8v*)(Mb + (size_t)orow * 64 + 32 + q * 8) = m1;
    }

    // fused per-column stats over this wave's 16 rows (pad rows masked)
#pragma unroll
    for (int t = 0; t < 4; ++t) {
        float sv = 0.f, qv = 0.f;
#pragma unroll
        for (int r = 0; r < 4; ++r) {
            int row = r0 + q * 4 + r;
            float v = (row < NN) ? acc2[t][r] : 0.f;
            sv += v;
            qv = fmaf(v, v, qv);
        }
        sv += __shfl_xor(sv, 16); sv += __shfl_xor(sv, 32);
        qv += __shfl_xor(qv, 16); qv += __shfl_xor(qv, 32);
        if (lane < 16) {
            sred[0][w][t * 16 + cl] = sv;
            sred[1][w][t * 16 + cl] = qv;
        }
    }
    __syncthreads();
    int tt = threadIdx.x;
    if (tt < 128) {
        int which = tt >> 6, c = tt & 63;
        float tot = sred[which][0][c] + sred[which][1][c] +
                    sred[which][2][c] + sred[which][3][c];
        atomicAdd(&statsL[which * 64 + c], tot);
    }
}

// final BN apply from bf16 Mb (affine inline, no relu, f32 out).
// Stats are exact f32; only z is bf16-rounded (error ~2^-9 * |z_norm|).
__global__ __launch_bounds__(256) void k_apply_aff(const unsigned short* __restrict__ Mb,
                                                   const float* __restrict__ statsL,
                                                   const float* __restrict__ gammaL,
                                                   const float* __restrict__ betaL,
                                                   float* __restrict__ out) {
    __shared__ float sa[64];
    __shared__ float sc[64];
    int t = threadIdx.x;
    if (t < 64) {
        float mean = statsL[t] * (1.f / NN);
        float var = statsL[64 + t] * (1.f / NN) - mean * mean;
        float a = gammaL[t] * rsqrtf(var + BN_EPS);
        sa[t] = a;
        sc[t] = fmaf(-mean, a, betaL[t]);
    }
    __syncthreads();
    int i4 = blockIdx.x * 256 + t;     // float4 index over NN*16
    if (i4 >= NN * 16) return;
    int cb = (i4 & 15) * 4;
    uint2 p = *(const uint2*)(Mb + (size_t)i4 * 4);
    union { unsigned u; float f; } w0, w1, w2, w3;
    w0.u = p.x << 16; w1.u = p.x & 0xffff0000u;
    w2.u = p.y << 16; w3.u = p.y & 0xffff0000u;
    float4 o;
    o.x = fmaf(w0.f, sa[cb + 0], sc[cb + 0]);
    o.y = fmaf(w1.f, sa[cb + 1], sc[cb + 1]);
    o.z = fmaf(w2.f, sa[cb + 2], sc[cb + 2]);
    o.w = fmaf(w3.f, sa[cb + 3], sc[cb + 3]);
    ((float4*)out)[i4] = o;
}

extern "C" void kernel_launch(void* const* d_in, const int* in_sizes, int n_in,
                              void* d_out, int out_size, void* d_ws, size_t ws_size,
                              hipStream_t stream) {
    const float* x     = (const float*)d_in[0];
    const int*   ei    = (const int*)d_in[1];   // [2][E]
    const float* W1    = (const float*)d_in[2];
    const float* b1    = (const float*)d_in[3];
    const float* W2    = (const float*)d_in[4];
    const float* b2    = (const float*)d_in[5];
    const float* gamma = (const float*)d_in[6];
    const float* beta  = (const float*)d_in[7];
    float* out = (float*)d_out;

    const int* src = ei;        // edge_index[0]
    const int* dst = ei + EE;   // edge_index[1]

    char* w = (char*)d_ws;
    unsigned*       Ab  = (unsigned*)w;       w += (size_t)NPAD * DD * 2;   // bf16 agg out
    unsigned*       Mb  = (unsigned*)w;       w += (size_t)NPAD * DD * 2;   // bf16 mlp out
    unsigned*       Xb  = (unsigned*)w;       w += (size_t)NPAD * DD * 2;   // bf16 x
    unsigned short* col = (unsigned short*)w; w += (size_t)NN * CAP * 2;    // u16 padded CSR
    unsigned*       bucket = (unsigned*)w;    w += (size_t)NPART * BCAP * 4;
    int*            cursor    = (int*)w;      w += (size_t)NN * 4;          // degree after scatter
    int*            bucketCnt = (int*)w;      w += 128 * 4;
    float*          stats     = (float*)w;    w += 384 * 4;                 // 3 layers x 128
    unsigned short* Wb        = (unsigned short*)w; w += 3 * 2 * 4096 * 2;  // bf16 W^T

    // ---- setup + CSR build ----
    k_zero<<<1, 512, 0, stream>>>(bucketCnt, stats);
    k_build<<<NB_BUILD, 1024, 0, stream>>>(src, dst, bucket, bucketCnt, cursor,
                                           x, Xb, Mb, col, W1, W2, Wb);
    k_scatter<<<NPART * NSCAT, 256, 0, stream>>>(bucket, bucketCnt, cursor, col);

    // ---- layer 0 ----
    k_agg4<0><<<NB_AGG, 256, 0, stream>>>(Xb, cursor, col, nullptr, nullptr, nullptr, Ab);
    k_mlp_mfma<<<NB_MLP, 256, 0, stream>>>((unsigned short*)Ab, Wb, b1, b2,
                                           (unsigned short*)Mb, stats);

    // ---- layer 1 (BN0+ReLU fused into the gather) ----
    k_agg4<1><<<NB_AGG, 256, 0, stream>>>(Mb, cursor, col, stats, gamma, beta, Ab);
    k_mlp_mfma<<<NB_MLP, 256, 0, stream>>>((unsigned short*)Ab, Wb + 8192, b1 + 64, b2 + 64,
                                           (unsigned short*)Mb, stats + 128);

    // ---- layer 2 (BN1+ReLU fused into the gather) ----
    k_agg4<1><<<NB_AGG, 256, 0, stream>>>(Mb, cursor, col, stats + 128, gamma + 64, beta + 64, Ab);
    k_mlp_mfma<<<NB_MLP, 256, 0, stream>>>((unsigned short*)Ab, Wb + 16384, b1 + 128, b2 + 128,
                                           (unsigned short*)Mb, stats + 256);

    // ---- final BN apply from bf16 Mb (no relu, f32 out) ----
    k_apply_aff<<<NB_APPLY, 256, 0, stream>>>((unsigned short*)Mb, stats + 256,
                                              gamma + 128, beta + 128, out);
}

// Round 23
// 214.734 us; speedup vs baseline: 1.0349x; 1.0349x over previous
//
#include <hip/hip_runtime.h>

#define NN 50000
#define NPAD 50064             // padded rows (>= NN+64) for MFMA tail + zero pad row
#define EE 800000
#define DD 64
#define BN_EPS 1e-5f

#define NPART 8
#define PART_NODES 6250        // 50000/8
#define CAP 64                 // padded CSR slots per node (u16)
#define SENT2 0xC350C350u      // two u16 sentinels (50000,50000)
#define BCAP 131072            // bucket capacity per partition (u32 entries)
#define NSCAT 32               // scatter blocks per partition
#define NB_BUILD 782           // ceil(800000/1024)
#define NB_AGG  12500          // 4 nodes (waves) per 256-thr block, grid exact
#define NB_MLP  782            // 64 rows per block (4 waves x 16)
#define NB_APPLY 3125

typedef __attribute__((ext_vector_type(8))) short short8v;   // 8 bf16 = 4 VGPR
typedef __attribute__((ext_vector_type(4))) float float4v;   // MFMA acc

__device__ __forceinline__ unsigned bfpack2(float a, float b) {
    union { float f; unsigned u; } ua, ub;
    ua.f = a; ub.f = b;
    unsigned ra = ua.u + 0x7fffu + ((ua.u >> 16) & 1u);
    unsigned rb = ub.u + 0x7fffu + ((ub.u >> 16) & 1u);
    return (ra >> 16) | (rb & 0xffff0000u);
}

__device__ __forceinline__ unsigned short bf16of(float v) {
    union { float f; unsigned u; } x; x.f = v;
    unsigned r = x.u + 0x7fffu + ((x.u >> 16) & 1u);
    return (unsigned short)(r >> 16);
}

// zero small control state (bucketCnt + 3x128 stats)
__global__ void k_zero(int* __restrict__ bucketCnt, float* __restrict__ stats) {
    int t = threadIdx.x;
    if (t < 128) bucketCnt[t] = 0;
    if (t < 384) stats[t] = 0.f;
}

// build: bucket edges by dst partition (u32-packed s<<13|dlocal), zero cursor,
// cvt x -> bf16, prep W -> bf16, sentinel-fill col (u16) + zero pad rows.
__global__ __launch_bounds__(1024) void k_build(const int* __restrict__ src,
                                                const int* __restrict__ dst,
                                                unsigned* __restrict__ bucket,
                                                int* __restrict__ bucketCnt,
                                                int* __restrict__ cursor,
                                                const float* __restrict__ x,
                                                unsigned* __restrict__ xb,
                                                unsigned* __restrict__ mb,
                                                unsigned short* __restrict__ col,
                                                const float* __restrict__ W1,
                                                const float* __restrict__ W2,
                                                unsigned short* __restrict__ Wb) {
    __shared__ int lcnt[8];
    __shared__ int lbase[8];
    int t = threadIdx.x;
    int g = blockIdx.x * 1024 + t;
    if (g < NN) cursor[g] = 0;
    if (g < NN * 8) {
        const float4* p = (const float4*)(x + (size_t)g * 8);
        float4 a = p[0], b = p[1];
        uint4 o;
        o.x = bfpack2(a.x, a.y); o.y = bfpack2(a.z, a.w);
        o.z = bfpack2(b.x, b.y); o.w = bfpack2(b.z, b.w);
        ((uint4*)xb)[g] = o;
    }
    if (g < 3 * 2 * 4096) {
        int l = g / 8192;
        int rem = g - l * 8192;
        int m = rem / 4096;
        int e = rem - m * 4096;
        int c = e >> 6, k = e & 63;
        const float* W = (m == 0 ? W1 : W2) + l * 4096;
        Wb[g] = bf16of(W[k * 64 + c]);
    }
    // sentinel-fill first 32 u16 slots of every node (16 u32 writes per node)
    {
        unsigned* col32 = (unsigned*)col;
        if (g < NN * 16)
            col32[(g >> 4) * 32 + (g & 15)] = SENT2;
    }
    // zero the pad rows (row NN..) so sentinel gathers read 0
    if (g < 64 * 32) { xb[NN * 32 + g] = 0; mb[NN * 32 + g] = 0; }
    if (t < 8) lcnt[t] = 0;
    __syncthreads();
    int p = 0, loc = 0;
    unsigned pk = 0;
    bool ok = (g < EE);
    if (ok) {
        int d = __builtin_nontemporal_load(dst + g);
        int s = __builtin_nontemporal_load(src + g);
        p = (unsigned)d / PART_NODES;
        pk = ((unsigned)s << 13) | (unsigned)(d - p * PART_NODES);
        loc = atomicAdd(&lcnt[p], 1);
    }
    __syncthreads();
    if (t < 8) lbase[t] = atomicAdd(&bucketCnt[t * 16], lcnt[t]);
    __syncthreads();
    if (ok) bucket[(size_t)p * BCAP + lbase[p] + loc] = pk;
}

// scatter bucket p into col slice p (u16 stores; dirty lines stay on one XCD)
__global__ __launch_bounds__(256) void k_scatter(const unsigned* __restrict__ bucket,
                                                 const int* __restrict__ bucketCnt,
                                                 int* __restrict__ cursor,
                                                 unsigned short* __restrict__ col) {
    int p = blockIdx.x & 7;
    int cnt = bucketCnt[p * 16];
    int dbase = p * PART_NODES;
    const unsigned* b = bucket + (size_t)p * BCAP;
    for (int i = (blockIdx.x >> 3) * 256 + threadIdx.x; i < cnt; i += NSCAT * 256) {
        unsigned v = __builtin_nontemporal_load(b + i);
        int d = dbase + (int)(v & 8191u);
        int s = (int)(v >> 13);
        int pos = atomicAdd(&cursor[d], 1);
        col[d * CAP + pos] = (unsigned short)s;
    }
}

// z[i,:] = self + sum_j val(h[j,:]); val = relu(a*x+c) when FUSE.
// Branchless first 24 slots (P(deg<=24)=97.8%): sentinel pad -> zero row,
// cancelled via fmaf(mask,...). Rare deg>24 handled by tail loop reading the
// real values in slots 24..dn. 3 col loads + 3 gathers issue with NO deg dep.
template<int FUSE>
__global__ __launch_bounds__(256) void k_agg4(const unsigned* __restrict__ hb,
                                              const int* __restrict__ deg,
                                              const unsigned short* __restrict__ col,
                                              const float* __restrict__ statsL,
                                              const float* __restrict__ gammaL,
                                              const float* __restrict__ betaL,
                                              unsigned* __restrict__ outZb) {
    __shared__ float sa[64];
    __shared__ float sc[64];
    if (FUSE) {
        int tt = threadIdx.x;
        if (tt < 64) {
            float mean = statsL[tt] * (1.f / NN);
            float var = statsL[64 + tt] * (1.f / NN) - mean * mean;
            float a = gammaL[tt] * rsqrtf(var + BN_EPS);
            sa[tt] = a;
            sc[tt] = fmaf(-mean, a, betaL[tt]);
        }
        __syncthreads();
    }
    int node = blockIdx.x * 4 + (threadIdx.x >> 6);   // grid exact: 12500*4
    int lane = threadIdx.x & 63;
    int li = lane & 7;
    int slot = lane >> 3;
    int base = node * CAP;
    // 3 independent u16 col loads, issued before anything depends on deg
    int s0 = col[base + slot];
    int s1 = col[base + slot + 8];
    int s2 = col[base + slot + 16];
    int dn = deg[node];            // only gates the rare >24 tail
    const uint4* hb4 = (const uint4*)hb;
    uint4 u0 = hb4[(size_t)s0 * 8 + li];
    uint4 u1 = hb4[(size_t)s1 * 8 + li];
    uint4 u2 = hb4[(size_t)s2 * 8 + li];
    float m0 = (s0 < NN) ? 1.f : 0.f;
    float m1 = (s1 < NN) ? 1.f : 0.f;
    float m2 = (s2 < NN) ? 1.f : 0.f;

    float a8[8], c8[8];
    if (FUSE) {
#pragma unroll
        for (int j = 0; j < 8; ++j) { a8[j] = sa[li * 8 + j]; c8[j] = sc[li * 8 + j]; }
    }
    float acc[8];
#pragma unroll
    for (int i = 0; i < 8; ++i) acc[i] = 0.f;

#define UNPK_ADD_M(U, M)                                                 \
    {                                                                    \
        uint4 _u = (U);                                                  \
        union { unsigned u; float f; } l0, h0, l1, h1, l2, h2, l3, h3;   \
        l0.u = _u.x << 16; h0.u = _u.x & 0xffff0000u;                    \
        l1.u = _u.y << 16; h1.u = _u.y & 0xffff0000u;                    \
        l2.u = _u.z << 16; h2.u = _u.z & 0xffff0000u;                    \
        l3.u = _u.w << 16; h3.u = _u.w & 0xffff0000u;                    \
        float v[8] = {l0.f, h0.f, l1.f, h1.f, l2.f, h2.f, l3.f, h3.f};   \
        _Pragma("unroll")                                                \
        for (int j = 0; j < 8; ++j) {                                    \
            float y = FUSE ? fmaxf(fmaf(v[j], a8[j], c8[j]), 0.f) : v[j];\
            acc[j] = fmaf((M), y, acc[j]);                               \
        }                                                                \
    }

    if (slot == 0)
        UNPK_ADD_M(hb4[(size_t)node * 8 + li], 1.f);   // self row

    UNPK_ADD_M(u0, m0);
    UNPK_ADD_M(u1, m1);
    UNPK_ADD_M(u2, m2);

    if (dn > 24) {                 // rare tail (P ~ 2.2% per node)
        for (int k = 24 + slot; k < dn; k += 8) {
            int s = col[base + k];
            UNPK_ADD_M(hb4[(size_t)s * 8 + li], 1.f);
        }
    }
#undef UNPK_ADD_M

#pragma unroll
    for (int i = 0; i < 8; ++i) acc[i] += __shfl_xor(acc[i], 8);
#pragma unroll
    for (int i = 0; i < 8; ++i) acc[i] += __shfl_xor(acc[i], 16);
#pragma unroll
    for (int i = 0; i < 8; ++i) acc[i] += __shfl_xor(acc[i], 32);

    if (slot == 0) {
        uint4 o;
        o.x = bfpack2(acc[0], acc[1]);
        o.y = bfpack2(acc[2], acc[3]);
        o.z = bfpack2(acc[4], acc[5]);
        o.w = bfpack2(acc[6], acc[7]);
        ((uint4*)outZb)[(size_t)node * 8 + li] = o;
    }
}

// MFMA MLP + fused BN stats; always writes bf16 Mb (LDS repack, 16B stores).
// Stats from f32 acc2 (exact).
__global__ __launch_bounds__(256) void k_mlp_mfma(const unsigned short* __restrict__ Zb,
                                                  const unsigned short* __restrict__ WbL,
                                                  const float* __restrict__ b1,
                                                  const float* __restrict__ b2,
                                                  unsigned short* __restrict__ Mb,
                                                  float* __restrict__ statsL) {
    __shared__ unsigned short sm[4][16 * 72];   // padded stride 72 u16
    __shared__ float sred[2][4][64];
    int w = threadIdx.x >> 6;
    int lane = threadIdx.x & 63;
    int q = lane >> 4;
    int cl = lane & 15;
    int r0 = blockIdx.x * 64 + w * 16;

    short8v B1[4][2], B2[4][2];
#pragma unroll
    for (int t = 0; t < 4; ++t) {
#pragma unroll
        for (int h = 0; h < 2; ++h) {
            B1[t][h] = *(const short8v*)(WbL + ((t * 16 + cl) * 64 + h * 32 + q * 8));
            B2[t][h] = *(const short8v*)(WbL + 4096 + ((t * 16 + cl) * 64 + h * 32 + q * 8));
        }
    }

    const unsigned short* zr = Zb + (size_t)(r0 + cl) * 64;
    short8v a0 = *(const short8v*)(zr + q * 8);
    short8v a1 = *(const short8v*)(zr + 32 + q * 8);

    float4v acc1[4];
#pragma unroll
    for (int t = 0; t < 4; ++t) {
        float b = b1[t * 16 + cl];
        acc1[t] = (float4v){b, b, b, b};
        acc1[t] = __builtin_amdgcn_mfma_f32_16x16x32_bf16(a0, B1[t][0], acc1[t], 0, 0, 0);
        acc1[t] = __builtin_amdgcn_mfma_f32_16x16x32_bf16(a1, B1[t][1], acc1[t], 0, 0, 0);
    }

    unsigned short* s = sm[w];
#pragma unroll
    for (int t = 0; t < 4; ++t) {
#pragma unroll
        for (int r = 0; r < 4; ++r) {
            float v = fmaxf(acc1[t][r], 0.f);
            s[(q * 4 + r) * 72 + t * 16 + cl] = bf16of(v);
        }
    }

    short8v a2_0 = *(const short8v*)(s + cl * 72 + q * 8);
    short8v a2_1 = *(const short8v*)(s + cl * 72 + 32 + q * 8);

    float4v acc2[4];
#pragma unroll
    for (int t = 0; t < 4; ++t) {
        float b = b2[t * 16 + cl];
        acc2[t] = (float4v){b, b, b, b};
        acc2[t] = __builtin_amdgcn_mfma_f32_16x16x32_bf16(a2_0, B2[t][0], acc2[t], 0, 0, 0);
        acc2[t] = __builtin_amdgcn_mfma_f32_16x16x32_bf16(a2_1, B2[t][1], acc2[t], 0, 0, 0);
    }

    // bf16 repack through LDS tile -> 16B coalesced stores
#pragma unroll
    for (int t = 0; t < 4; ++t) {
#pragma unroll
        for (int r = 0; r < 4; ++r) {
            s[(q * 4 + r) * 72 + t * 16 + cl] = bf16of(acc2[t][r]);
        }
    }
    short8v m0 = *(const short8v*)(s + cl * 72 + q * 8);
    short8v m1 = *(const short8v*)(s + cl * 72 + 32 + q * 8);
    int orow = r0 + cl;
    if (orow < NN) {
        *(short8v*)(Mb + (size_t)orow * 64 + q * 8) = m0;
        *(short8v*)(Mb + (size_t)orow * 64 + 32 + q * 8) = m1;
    }

    // fused per-column stats over this wave's 16 rows (pad rows masked)
#pragma unroll
    for (int t = 0; t < 4; ++t) {
        float sv = 0.f, qv = 0.f;
#pragma unroll
        for (int r = 0; r < 4; ++r) {
            int row = r0 + q * 4 + r;
            float v = (row < NN) ? acc2[t][r] : 0.f;
            sv += v;
            qv = fmaf(v, v, qv);
        }
        sv += __shfl_xor(sv, 16); sv += __shfl_xor(sv, 32);
        qv += __shfl_xor(qv, 16); qv += __shfl_xor(qv, 32);
        if (lane < 16) {
            sred[0][w][t * 16 + cl] = sv;
            sred[1][w][t * 16 + cl] = qv;
        }
    }
    __syncthreads();
    int tt = threadIdx.x;
    if (tt < 128) {
        int which = tt >> 6, c = tt & 63;
        float tot = sred[which][0][c] + sred[which][1][c] +
                    sred[which][2][c] + sred[which][3][c];
        atomicAdd(&statsL[which * 64 + c], tot);
    }
}

// final BN apply from bf16 Mb (affine inline, no relu, f32 out).
__global__ __launch_bounds__(256) void k_apply_aff(const unsigned short* __restrict__ Mb,
                                                   const float* __restrict__ statsL,
                                                   const float* __restrict__ gammaL,
                                                   const float* __restrict__ betaL,
                                                   float* __restrict__ out) {
    __shared__ float sa[64];
    __shared__ float sc[64];
    int t = threadIdx.x;
    if (t < 64) {
        float mean = statsL[t] * (1.f / NN);
        float var = statsL[64 + t] * (1.f / NN) - mean * mean;
        float a = gammaL[t] * rsqrtf(var + BN_EPS);
        sa[t] = a;
        sc[t] = fmaf(-mean, a, betaL[t]);
    }
    __syncthreads();
    int i4 = blockIdx.x * 256 + t;     // float4 index over NN*16
    if (i4 >= NN * 16) return;
    int cb = (i4 & 15) * 4;
    uint2 p = *(const uint2*)(Mb + (size_t)i4 * 4);
    union { unsigned u; float f; } w0, w1, w2, w3;
    w0.u = p.x << 16; w1.u = p.x & 0xffff0000u;
    w2.u = p.y << 16; w3.u = p.y & 0xffff0000u;
    float4 o;
    o.x = fmaf(w0.f, sa[cb + 0], sc[cb + 0]);
    o.y = fmaf(w1.f, sa[cb + 1], sc[cb + 1]);
    o.z = fmaf(w2.f, sa[cb + 2], sc[cb + 2]);
    o.w = fmaf(w3.f, sa[cb + 3], sc[cb + 3]);
    ((float4*)out)[i4] = o;
}

extern "C" void kernel_launch(void* const* d_in, const int* in_sizes, int n_in,
                              void* d_out, int out_size, void* d_ws, size_t ws_size,
                              hipStream_t stream) {
    const float* x     = (const float*)d_in[0];
    const int*   ei    = (const int*)d_in[1];   // [2][E]
    const float* W1    = (const float*)d_in[2];
    const float* b1    = (const float*)d_in[3];
    const float* W2    = (const float*)d_in[4];
    const float* b2    = (const float*)d_in[5];
    const float* gamma = (const float*)d_in[6];
    const float* beta  = (const float*)d_in[7];
    float* out = (float*)d_out;

    const int* src = ei;        // edge_index[0]
    const int* dst = ei + EE;   // edge_index[1]

    char* w = (char*)d_ws;
    unsigned*       Ab  = (unsigned*)w;       w += (size_t)NPAD * DD * 2;   // bf16 agg out
    unsigned*       Mb  = (unsigned*)w;       w += (size_t)NPAD * DD * 2;   // bf16 mlp out
    unsigned*       Xb  = (unsigned*)w;       w += (size_t)NPAD * DD * 2;   // bf16 x
    unsigned short* col = (unsigned short*)w; w += (size_t)NN * CAP * 2;    // u16 padded CSR
    unsigned*       bucket = (unsigned*)w;    w += (size_t)NPART * BCAP * 4;
    int*            cursor    = (int*)w;      w += (size_t)NN * 4;          // degree after scatter
    int*            bucketCnt = (int*)w;      w += 128 * 4;
    float*          stats     = (float*)w;    w += 384 * 4;                 // 3 layers x 128
    unsigned short* Wb        = (unsigned short*)w; w += 3 * 2 * 4096 * 2;  // bf16 W^T

    // ---- setup + CSR build ----
    k_zero<<<1, 512, 0, stream>>>(bucketCnt, stats);
    k_build<<<NB_BUILD, 1024, 0, stream>>>(src, dst, bucket, bucketCnt, cursor,
                                           x, Xb, Mb, col, W1, W2, Wb);
    k_scatter<<<NPART * NSCAT, 256, 0, stream>>>(bucket, bucketCnt, cursor, col);

    // ---- layer 0 ----
    k_agg4<0><<<NB_AGG, 256, 0, stream>>>(Xb, cursor, col, nullptr, nullptr, nullptr, Ab);
    k_mlp_mfma<<<NB_MLP, 256, 0, stream>>>((unsigned short*)Ab, Wb, b1, b2,
                                           (unsigned short*)Mb, stats);

    // ---- layer 1 (BN0+ReLU fused into the gather) ----
    k_agg4<1><<<NB_AGG, 256, 0, stream>>>(Mb, cursor, col, stats, gamma, beta, Ab);
    k_mlp_mfma<<<NB_MLP, 256, 0, stream>>>((unsigned short*)Ab, Wb + 8192, b1 + 64, b2 + 64,
                                           (unsigned short*)Mb, stats + 128);

    // ---- layer 2 (BN1+ReLU fused into the gather) ----
    k_agg4<1><<<NB_AGG, 256, 0, stream>>>(Mb, cursor, col, stats + 128, gamma + 64, beta + 64, Ab);
    k_mlp_mfma<<<NB_MLP, 256, 0, stream>>>((unsigned short*)Ab, Wb + 16384, b1 + 128, b2 + 128,
                                           (unsigned short*)Mb, stats + 256);

    // ---- final BN apply from bf16 Mb (no relu, f32 out) ----
    k_apply_aff<<<NB_APPLY, 256, 0, stream>>>((unsigned short*)Mb, stats + 256,
                                              gamma + 128, beta + 128, out);
}

// Round 26
// 213.188 us; speedup vs baseline: 1.0424x; 1.0073x over previous
//
#include <hip/hip_runtime.h>

#define NN 50000
#define NPAD 50064             // padded rows (>= NN+64) for MFMA tail + zero pad row
#define EE 800000
#define DD 64
#define BN_EPS 1e-5f

#define NPART 8
#define PART_NODES 6250        // 50000/8
#define CAP 64                 // padded CSR slots per node (u16)
#define SENT2 0xC350C350u      // two u16 sentinels (50000,50000)
#define BCAP 131072            // bucket capacity per partition (u32 entries)
#define NSCAT 32               // scatter blocks per partition
#define NB_BUILD 782           // ceil(800000/1024)
#define NB_AGG  12500          // 4 nodes (waves) per 256-thr block, grid exact
#define NB_MLP  782            // 64 rows per block (4 waves x 16)
#define NB_APPLY 3125

typedef __attribute__((ext_vector_type(8))) short short8v;   // 8 bf16 = 4 VGPR
typedef __attribute__((ext_vector_type(4))) float float4v;   // MFMA acc

__device__ __forceinline__ unsigned bfpack2(float a, float b) {
    union { float f; unsigned u; } ua, ub;
    ua.f = a; ub.f = b;
    unsigned ra = ua.u + 0x7fffu + ((ua.u >> 16) & 1u);
    unsigned rb = ub.u + 0x7fffu + ((ub.u >> 16) & 1u);
    return (ra >> 16) | (rb & 0xffff0000u);
}

__device__ __forceinline__ unsigned short bf16of(float v) {
    union { float f; unsigned u; } x; x.f = v;
    unsigned r = x.u + 0x7fffu + ((x.u >> 16) & 1u);
    return (unsigned short)(r >> 16);
}

// zero small control state (bucketCnt + 3x128 stats)
__global__ void k_zero(int* __restrict__ bucketCnt, float* __restrict__ stats) {
    int t = threadIdx.x;
    if (t < 128) bucketCnt[t] = 0;
    if (t < 384) stats[t] = 0.f;
}

// build: bucket edges by dst partition (u32-packed s<<13|dlocal), cursor=1
// (slot 0 = self), cvt x -> bf16, prep W -> bf16, sentinel-fill col with
// self id in slot 0 + zero pad rows.
__global__ __launch_bounds__(1024) void k_build(const int* __restrict__ src,
                                                const int* __restrict__ dst,
                                                unsigned* __restrict__ bucket,
                                                int* __restrict__ bucketCnt,
                                                int* __restrict__ cursor,
                                                const float* __restrict__ x,
                                                unsigned* __restrict__ xb,
                                                unsigned* __restrict__ mb,
                                                unsigned short* __restrict__ col,
                                                const float* __restrict__ W1,
                                                const float* __restrict__ W2,
                                                unsigned short* __restrict__ Wb) {
    __shared__ int lcnt[8];
    __shared__ int lbase[8];
    int t = threadIdx.x;
    int g = blockIdx.x * 1024 + t;
    if (g < NN) cursor[g] = 1;         // slot 0 reserved for self
    if (g < NN * 8) {
        const float4* p = (const float4*)(x + (size_t)g * 8);
        float4 a = p[0], b = p[1];
        uint4 o;
        o.x = bfpack2(a.x, a.y); o.y = bfpack2(a.z, a.w);
        o.z = bfpack2(b.x, b.y); o.w = bfpack2(b.z, b.w);
        ((uint4*)xb)[g] = o;
    }
    if (g < 3 * 2 * 4096) {
        int l = g / 8192;
        int rem = g - l * 8192;
        int m = rem / 4096;
        int e = rem - m * 4096;
        int c = e >> 6, k = e & 63;
        const float* W = (m == 0 ? W1 : W2) + l * 4096;
        Wb[g] = bf16of(W[k * 64 + c]);
    }
    // sentinel-fill first 32 u16 slots of every node; pair 0 carries self id
    {
        unsigned* col32 = (unsigned*)col;
        if (g < NN * 16) {
            int n = g >> 4;
            unsigned v = ((g & 15) == 0) ? ((SENT2 & 0xffff0000u) | (unsigned)n)
                                         : SENT2;
            col32[n * 32 + (g & 15)] = v;
        }
    }
    // zero the pad rows (row NN..) so sentinel gathers read 0
    if (g < 64 * 32) { xb[NN * 32 + g] = 0; mb[NN * 32 + g] = 0; }
    if (t < 8) lcnt[t] = 0;
    __syncthreads();
    int p = 0, loc = 0;
    unsigned pk = 0;
    bool ok = (g < EE);
    if (ok) {
        int d = __builtin_nontemporal_load(dst + g);
        int s = __builtin_nontemporal_load(src + g);
        p = (unsigned)d / PART_NODES;
        pk = ((unsigned)s << 13) | (unsigned)(d - p * PART_NODES);
        loc = atomicAdd(&lcnt[p], 1);
    }
    __syncthreads();
    if (t < 8) lbase[t] = atomicAdd(&bucketCnt[t * 16], lcnt[t]);
    __syncthreads();
    if (ok) bucket[(size_t)p * BCAP + lbase[p] + loc] = pk;
}

// scatter bucket p into col slice p (u16 stores; slots 1..deg after self)
__global__ __launch_bounds__(256) void k_scatter(const unsigned* __restrict__ bucket,
                                                 const int* __restrict__ bucketCnt,
                                                 int* __restrict__ cursor,
                                                 unsigned short* __restrict__ col) {
    int p = blockIdx.x & 7;
    int cnt = bucketCnt[p * 16];
    int dbase = p * PART_NODES;
    const unsigned* b = bucket + (size_t)p * BCAP;
    for (int i = (blockIdx.x >> 3) * 256 + threadIdx.x; i < cnt; i += NSCAT * 256) {
        unsigned v = __builtin_nontemporal_load(b + i);
        int d = dbase + (int)(v & 8191u);
        int s = (int)(v >> 13);
        int pos = atomicAdd(&cursor[d], 1);
        col[d * CAP + pos] = (unsigned short)s;
    }
}

// z[i,:] = sum over slots of val(h[col[slot],:]); slot 0 = self (id in CSR).
// Branchless first 24 slots (covers self + 23 nbrs; P(deg>23)=3.7% -> tail).
// val = relu(a*x+c) when FUSE; sentinel slots cancelled via fmaf(mask,...).
template<int FUSE>
__global__ __launch_bounds__(256) void k_agg4(const unsigned* __restrict__ hb,
                                              const int* __restrict__ deg,
                                              const unsigned short* __restrict__ col,
                                              const float* __restrict__ statsL,
                                              const float* __restrict__ gammaL,
                                              const float* __restrict__ betaL,
                                              unsigned* __restrict__ outZb) {
    __shared__ float sa[64];
    __shared__ float sc[64];
    if (FUSE) {
        int tt = threadIdx.x;
        if (tt < 64) {
            float mean = statsL[tt] * (1.f / NN);
            float var = statsL[64 + tt] * (1.f / NN) - mean * mean;
            float a = gammaL[tt] * rsqrtf(var + BN_EPS);
            sa[tt] = a;
            sc[tt] = fmaf(-mean, a, betaL[tt]);
        }
        __syncthreads();
    }
    int node = blockIdx.x * 4 + (threadIdx.x >> 6);   // grid exact: 12500*4
    int lane = threadIdx.x & 63;
    int li = lane & 7;
    int slot = lane >> 3;
    int base = node * CAP;
    // 3 independent u16 col loads, issued before anything depends on deg
    int s0 = col[base + slot];
    int s1 = col[base + slot + 8];
    int s2 = col[base + slot + 16];
    int dn = deg[node];            // = 1 + degree; only gates the rare >24 tail
    const uint4* hb4 = (const uint4*)hb;
    uint4 u0 = hb4[(size_t)s0 * 8 + li];
    uint4 u1 = hb4[(size_t)s1 * 8 + li];
    uint4 u2 = hb4[(size_t)s2 * 8 + li];
    float m0 = (s0 < NN) ? 1.f : 0.f;
    float m1 = (s1 < NN) ? 1.f : 0.f;
    float m2 = (s2 < NN) ? 1.f : 0.f;

    float a8[8], c8[8];
    if (FUSE) {
#pragma unroll
        for (int j = 0; j < 8; ++j) { a8[j] = sa[li * 8 + j]; c8[j] = sc[li * 8 + j]; }
    }
    float acc[8];
#pragma unroll
    for (int i = 0; i < 8; ++i) acc[i] = 0.f;

#define UNPK_ADD_M(U, M)                                                 \
    {                                                                    \
        uint4 _u = (U);                                                  \
        union { unsigned u; float f; } l0, h0, l1, h1, l2, h2, l3, h3;   \
        l0.u = _u.x << 16; h0.u = _u.x & 0xffff0000u;                    \
        l1.u = _u.y << 16; h1.u = _u.y & 0xffff0000u;                    \
        l2.u = _u.z << 16; h2.u = _u.z & 0xffff0000u;                    \
        l3.u = _u.w << 16; h3.u = _u.w & 0xffff0000u;                    \
        float v[8] = {l0.f, h0.f, l1.f, h1.f, l2.f, h2.f, l3.f, h3.f};   \
        _Pragma("unroll")                                                \
        for (int j = 0; j < 8; ++j) {                                    \
            float y = FUSE ? fmaxf(fmaf(v[j], a8[j], c8[j]), 0.f) : v[j];\
            acc[j] = fmaf((M), y, acc[j]);                               \
        }                                                                \
    }

    UNPK_ADD_M(u0, m0);
    UNPK_ADD_M(u1, m1);
    UNPK_ADD_M(u2, m2);

    if (dn > 24) {                 // rare tail (deg > 23, P ~ 3.7%)
        for (int k = 24 + slot; k < dn; k += 8) {
            int s = col[base + k];
            UNPK_ADD_M(hb4[(size_t)s * 8 + li], 1.f);
        }
    }
#undef UNPK_ADD_M

#pragma unroll
    for (int i = 0; i < 8; ++i) acc[i] += __shfl_xor(acc[i], 8);
#pragma unroll
    for (int i = 0; i < 8; ++i) acc[i] += __shfl_xor(acc[i], 16);
#pragma unroll
    for (int i = 0; i < 8; ++i) acc[i] += __shfl_xor(acc[i], 32);

    if (slot == 0) {
        uint4 o;
        o.x = bfpack2(acc[0], acc[1]);
        o.y = bfpack2(acc[2], acc[3]);
        o.z = bfpack2(acc[4], acc[5]);
        o.w = bfpack2(acc[6], acc[7]);
        ((uint4*)outZb)[(size_t)node * 8 + li] = o;
    }
}

// MFMA MLP + fused BN stats; always writes bf16 Mb (LDS repack, 16B stores).
// Stats from f32 acc2 (exact).
__global__ __launch_bounds__(256) void k_mlp_mfma(const unsigned short* __restrict__ Zb,
                                                  const unsigned short* __restrict__ WbL,
                                                  const float* __restrict__ b1,
                                                  const float* __restrict__ b2,
                                                  unsigned short* __restrict__ Mb,
                                                  float* __restrict__ statsL) {
    __shared__ unsigned short sm[4][16 * 72];   // padded stride 72 u16
    __shared__ float sred[2][4][64];
    int w = threadIdx.x >> 6;
    int lane = threadIdx.x & 63;
    int q = lane >> 4;
    int cl = lane & 15;
    int r0 = blockIdx.x * 64 + w * 16;

    short8v B1[4][2], B2[4][2];
#pragma unroll
    for (int t = 0; t < 4; ++t) {
#pragma unroll
        for (int h = 0; h < 2; ++h) {
            B1[t][h] = *(const short8v*)(WbL + ((t * 16 + cl) * 64 + h * 32 + q * 8));
            B2[t][h] = *(const short8v*)(WbL + 4096 + ((t * 16 + cl) * 64 + h * 32 + q * 8));
        }
    }

    const unsigned short* zr = Zb + (size_t)(r0 + cl) * 64;
    short8v a0 = *(const short8v*)(zr + q * 8);
    short8v a1 = *(const short8v*)(zr + 32 + q * 8);

    float4v acc1[4];
#pragma unroll
    for (int t = 0; t < 4; ++t) {
        float b = b1[t * 16 + cl];
        acc1[t] = (float4v){b, b, b, b};
        acc1[t] = __builtin_amdgcn_mfma_f32_16x16x32_bf16(a0, B1[t][0], acc1[t], 0, 0, 0);
        acc1[t] = __builtin_amdgcn_mfma_f32_16x16x32_bf16(a1, B1[t][1], acc1[t], 0, 0, 0);
    }

    unsigned short* s = sm[w];
#pragma unroll
    for (int t = 0; t < 4; ++t) {
#pragma unroll
        for (int r = 0; r < 4; ++r) {
            float v = fmaxf(acc1[t][r], 0.f);
            s[(q * 4 + r) * 72 + t * 16 + cl] = bf16of(v);
        }
    }

    short8v a2_0 = *(const short8v*)(s + cl * 72 + q * 8);
    short8v a2_1 = *(const short8v*)(s + cl * 72 + 32 + q * 8);

    float4v acc2[4];
#pragma unroll
    for (int t = 0; t < 4; ++t) {
        float b = b2[t * 16 + cl];
        acc2[t] = (float4v){b, b, b, b};
        acc2[t] = __builtin_amdgcn_mfma_f32_16x16x32_bf16(a2_0, B2[t][0], acc2[t], 0, 0, 0);
        acc2[t] = __builtin_amdgcn_mfma_f32_16x16x32_bf16(a2_1, B2[t][1], acc2[t], 0, 0, 0);
    }

    // bf16 repack through LDS tile -> 16B coalesced stores
#pragma unroll
    for (int t = 0; t < 4; ++t) {
#pragma unroll
        for (int r = 0; r < 4; ++r) {
            s[(q * 4 + r) * 72 + t * 16 + cl] = bf16of(acc2[t][r]);
        }
    }
    short8v m0 = *(const short8v*)(s + cl * 72 + q * 8);
    short8v m1 = *(const short8v*)(s + cl * 72 + 32 + q * 8);
    int orow = r0 + cl;
    if (orow < NN) {
        *(short8v*)(Mb + (size_t)orow * 64 + q * 8) = m0;
        *(short8v*)(Mb + (size_t)orow * 64 + 32 + q * 8) = m1;
    }

    // fused per-column stats over this wave's 16 rows (pad rows masked)
#pragma unroll
    for (int t = 0; t < 4; ++t) {
        float sv = 0.f, qv = 0.f;
#pragma unroll
        for (int r = 0; r < 4; ++r) {
            int row = r0 + q * 4 + r;
            float v = (row < NN) ? acc2[t][r] : 0.f;
            sv += v;
            qv = fmaf(v, v, qv);
        }
        sv += __shfl_xor(sv, 16); sv += __shfl_xor(sv, 32);
        qv += __shfl_xor(qv, 16); qv += __shfl_xor(qv, 32);
        if (lane < 16) {
            sred[0][w][t * 16 + cl] = sv;
            sred[1][w][t * 16 + cl] = qv;
        }
    }
    __syncthreads();
    int tt = threadIdx.x;
    if (tt < 128) {
        int which = tt >> 6, c = tt & 63;
        float tot = sred[which][0][c] + sred[which][1][c] +
                    sred[which][2][c] + sred[which][3][c];
        atomicAdd(&statsL[which * 64 + c], tot);
    }
}

// final BN apply from bf16 Mb (affine inline, no relu, f32 out).
__global__ __launch_bounds__(256) void k_apply_aff(const unsigned short* __restrict__ Mb,
                                                   const float* __restrict__ statsL,
                                                   const float* __restrict__ gammaL,
                                                   const float* __restrict__ betaL,
                                                   float* __restrict__ out) {
    __shared__ float sa[64];
    __shared__ float sc[64];
    int t = threadIdx.x;
    if (t < 64) {
        float mean = statsL[t] * (1.f / NN);
        float var = statsL[64 + t] * (1.f / NN) - mean * mean;
        float a = gammaL[t] * rsqrtf(var + BN_EPS);
        sa[t] = a;
        sc[t] = fmaf(-mean, a, betaL[t]);
    }
    __syncthreads();
    int i4 = blockIdx.x * 256 + t;     // float4 index over NN*16
    if (i4 >= NN * 16) return;
    int cb = (i4 & 15) * 4;
    uint2 p = *(const uint2*)(Mb + (size_t)i4 * 4);
    union { unsigned u; float f; } w0, w1, w2, w3;
    w0.u = p.x << 16; w1.u = p.x & 0xffff0000u;
    w2.u = p.y << 16; w3.u = p.y & 0xffff0000u;
    float4 o;
    o.x = fmaf(w0.f, sa[cb + 0], sc[cb + 0]);
    o.y = fmaf(w1.f, sa[cb + 1], sc[cb + 1]);
    o.z = fmaf(w2.f, sa[cb + 2], sc[cb + 2]);
    o.w = fmaf(w3.f, sa[cb + 3], sc[cb + 3]);
    ((float4*)out)[i4] = o;
}

extern "C" void kernel_launch(void* const* d_in, const int* in_sizes, int n_in,
                              void* d_out, int out_size, void* d_ws, size_t ws_size,
                              hipStream_t stream) {
    const float* x     = (const float*)d_in[0];
    const int*   ei    = (const int*)d_in[1];   // [2][E]
    const float* W1    = (const float*)d_in[2];
    const float* b1    = (const float*)d_in[3];
    const float* W2    = (const float*)d_in[4];
    const float* b2    = (const float*)d_in[5];
    const float* gamma = (const float*)d_in[6];
    const float* beta  = (const float*)d_in[7];
    float* out = (float*)d_out;

    const int* src = ei;        // edge_index[0]
    const int* dst = ei + EE;   // edge_index[1]

    char* w = (char*)d_ws;
    unsigned*       Ab  = (unsigned*)w;       w += (size_t)NPAD * DD * 2;   // bf16 agg out
    unsigned*       Mb  = (unsigned*)w;       w += (size_t)NPAD * DD * 2;   // bf16 mlp out
    unsigned*       Xb  = (unsigned*)w;       w += (size_t)NPAD * DD * 2;   // bf16 x
    unsigned short* col = (unsigned short*)w; w += (size_t)NN * CAP * 2;    // u16 padded CSR
    unsigned*       bucket = (unsigned*)w;    w += (size_t)NPART * BCAP * 4;
    int*            cursor    = (int*)w;      w += (size_t)NN * 4;          // 1+degree after scatter
    int*            bucketCnt = (int*)w;      w += 128 * 4;
    float*          stats     = (float*)w;    w += 384 * 4;                 // 3 layers x 128
    unsigned short* Wb        = (unsigned short*)w; w += 3 * 2 * 4096 * 2;  // bf16 W^T

    // ---- setup + CSR build ----
    k_zero<<<1, 512, 0, stream>>>(bucketCnt, stats);
    k_build<<<NB_BUILD, 1024, 0, stream>>>(src, dst, bucket, bucketCnt, cursor,
                                           x, Xb, Mb, col, W1, W2, Wb);
    k_scatter<<<NPART * NSCAT, 256, 0, stream>>>(bucket, bucketCnt, cursor, col);

    // ---- layer 0 ----
    k_agg4<0><<<NB_AGG, 256, 0, stream>>>(Xb, cursor, col, nullptr, nullptr, nullptr, Ab);
    k_mlp_mfma<<<NB_MLP, 256, 0, stream>>>((unsigned short*)Ab, Wb, b1, b2,
                                           (unsigned short*)Mb, stats);

    // ---- layer 1 (BN0+ReLU fused into the gather) ----
    k_agg4<1><<<NB_AGG, 256, 0, stream>>>(Mb, cursor, col, stats, gamma, beta, Ab);
    k_mlp_mfma<<<NB_MLP, 256, 0, stream>>>((unsigned short*)Ab, Wb + 8192, b1 + 64, b2 + 64,
                                           (unsigned short*)Mb, stats + 128);

    // ---- layer 2 (BN1+ReLU fused into the gather) ----
    k_agg4<1><<<NB_AGG, 256, 0, stream>>>(Mb, cursor, col, stats + 128, gamma + 64, beta + 64, Ab);
    k_mlp_mfma<<<NB_MLP, 256, 0, stream>>>((unsigned short*)Ab, Wb + 16384, b1 + 128, b2 + 128,
                                           (unsigned short*)Mb, stats + 256);

    // ---- final BN apply from bf16 Mb (no relu, f32 out) ----
    k_apply_aff<<<NB_APPLY, 256, 0, stream>>>((unsigned short*)Mb, stats + 256,
                                              gamma + 128, beta + 128, out);
}